// Round 2
// baseline (165.198 us; speedup 1.0000x reference)
//
#include <hip/hip_runtime.h>
#include <math.h>

// N=65536 rows, D=256 fp32. out = sum_i (counts_i - 1)*d_i + exp(d_i)
// d_i = dot(z_a[i], z_b[i]); counts_i-1 = n-3 (i < n-1), n-2 (i == n-1).
// Memory-bound: 128 MiB read. Round-1 lesson: per-row serial load->shuffle
// chain left the kernel latency-bound (16 VGPRs, 42 us). Fix: 4 rows/wave
// batched loads + interleaved shuffle reductions, single kernel + atomicAdd.

#define D_DIM 256
#define ROWS 4            // rows per wave, fully unrolled
#define BLOCKS 4096       // 4096 blocks * 4 waves * 4 rows = 65536 rows

__global__ __launch_bounds__(256)
void dot_loss(const float* __restrict__ za,
              const float* __restrict__ zb,
              float* __restrict__ out,
              int n) {
    const int lane = threadIdx.x & 63;
    const int wave = threadIdx.x >> 6;
    const int waveId = blockIdx.x * 4 + wave;
    const int row0 = waveId * ROWS;

    // 64 lanes x float4 = one full 256-float row per load per row.
    const float4* a4 = (const float4*)za + (size_t)row0 * 64 + lane;
    const float4* b4 = (const float4*)zb + (size_t)row0 * 64 + lane;

    // Issue all 8 loads back-to-back (independent, 1 KiB each).
    float4 av[ROWS], bv[ROWS];
    #pragma unroll
    for (int r = 0; r < ROWS; ++r) av[r] = a4[(size_t)r * 64];
    #pragma unroll
    for (int r = 0; r < ROWS; ++r) bv[r] = b4[(size_t)r * 64];

    float d[ROWS];
    #pragma unroll
    for (int r = 0; r < ROWS; ++r) {
        float t = av[r].x * bv[r].x;
        t = fmaf(av[r].y, bv[r].y, t);
        t = fmaf(av[r].z, bv[r].z, t);
        t = fmaf(av[r].w, bv[r].w, t);
        d[r] = t;
    }

    // 6-step wave-64 reduction; 4 independent chains interleaved so the
    // ds_permute latency pipelines across rows.
    #pragma unroll
    for (int off = 32; off > 0; off >>= 1) {
        #pragma unroll
        for (int r = 0; r < ROWS; ++r)
            d[r] += __shfl_down(d[r], off);
    }

    float acc = 0.0f;
    if (lane == 0) {
        #pragma unroll
        for (int r = 0; r < ROWS; ++r) {
            int row = row0 + r;
            float coeff = (row == n - 1) ? (float)(n - 2) : (float)(n - 3);
            acc += coeff * d[r] + expf(d[r]);
        }
    }

    __shared__ float smem[4];
    if (lane == 0) smem[wave] = acc;
    __syncthreads();
    if (threadIdx.x == 0)
        atomicAdd(out, smem[0] + smem[1] + smem[2] + smem[3]);
}

extern "C" void kernel_launch(void* const* d_in, const int* in_sizes, int n_in,
                              void* d_out, int out_size, void* d_ws, size_t ws_size,
                              hipStream_t stream) {
    const float* za = (const float*)d_in[0];
    const float* zb = (const float*)d_in[1];
    float* out = (float*)d_out;
    const int n = in_sizes[0] / D_DIM;

    hipMemsetAsync(out, 0, sizeof(float), stream);
    dot_loss<<<BLOCKS, 256, 0, stream>>>(za, zb, out, n);
}

// Round 3
// 147.374 us; speedup vs baseline: 1.1209x; 1.1209x over previous
//
#include <hip/hip_runtime.h>
#include <math.h>

// N=65536 rows, D=256 fp32. out = sum_i (counts_i - 1)*d_i + exp(d_i)
// d_i = dot(z_a[i], z_b[i]); counts_i-1 = n-3 (i < n-1), n-2 (i == n-1).
//
// R1 lesson: 2 loads in flight per wave -> latency-bound, 42 us.
// R2 lesson: VGPR_Count=24 proved the compiler serialized the "batched"
//            loads; single-address atomicAdd added ~15 us of serialization.
// R3: fully-unrolled 8 rows/wave, all 16 float4 loads issued before any
//     reduction (64 VGPRs payload, __launch_bounds__(256,4) -> 128 budget),
//     partials + tiny reduce kernel (no atomics).

#define D_DIM 256
#define ROWS 8
#define BLOCKS 2048   // 2048 blocks * 4 waves * 8 rows = 65536 rows exactly

__global__ __launch_bounds__(256, 4)
void dot_loss_partial(const float4* __restrict__ za4,
                      const float4* __restrict__ zb4,
                      float* __restrict__ partial,
                      int n) {
    const int lane = threadIdx.x & 63;
    const int wave = threadIdx.x >> 6;
    const int waveId = blockIdx.x * 4 + wave;
    const int row0 = waveId * ROWS;

    const float4* a = za4 + (size_t)row0 * 64 + lane;
    const float4* b = zb4 + (size_t)row0 * 64 + lane;

    // Issue all 16 loads (8 rows x {a,b}) back-to-back: 16 KB in flight/wave.
    float4 av[ROWS], bv[ROWS];
    #pragma unroll
    for (int r = 0; r < ROWS; ++r) {
        av[r] = a[(size_t)r * 64];
        bv[r] = b[(size_t)r * 64];
    }

    float d[ROWS];
    #pragma unroll
    for (int r = 0; r < ROWS; ++r) {
        float t = av[r].x * bv[r].x;
        t = fmaf(av[r].y, bv[r].y, t);
        t = fmaf(av[r].z, bv[r].z, t);
        t = fmaf(av[r].w, bv[r].w, t);
        d[r] = t;
    }

    // 8 independent wave-64 reduction chains, interleaved so the
    // cross-lane-op latency pipelines across rows.
    #pragma unroll
    for (int off = 32; off > 0; off >>= 1) {
        #pragma unroll
        for (int r = 0; r < ROWS; ++r)
            d[r] += __shfl_down(d[r], off);
    }

    float acc = 0.0f;
    if (lane == 0) {
        #pragma unroll
        for (int r = 0; r < ROWS; ++r) {
            int row = row0 + r;
            float coeff = (row == n - 1) ? (float)(n - 2) : (float)(n - 3);
            acc += coeff * d[r] + expf(d[r]);
        }
    }

    __shared__ float smem[4];
    if (lane == 0) smem[wave] = acc;
    __syncthreads();
    if (threadIdx.x == 0)
        partial[blockIdx.x] = smem[0] + smem[1] + smem[2] + smem[3];
}

__global__ __launch_bounds__(256)
void reduce_partials(const float* __restrict__ partial,
                     float* __restrict__ out,
                     int m) {
    const int lane = threadIdx.x & 63;
    const int wave = threadIdx.x >> 6;
    double s = 0.0;
    for (int i = threadIdx.x; i < m; i += 256)
        s += (double)partial[i];
    #pragma unroll
    for (int off = 32; off > 0; off >>= 1)
        s += __shfl_down(s, off);
    __shared__ double smem[4];
    if (lane == 0) smem[wave] = s;
    __syncthreads();
    if (threadIdx.x == 0)
        out[0] = (float)(smem[0] + smem[1] + smem[2] + smem[3]);
}

extern "C" void kernel_launch(void* const* d_in, const int* in_sizes, int n_in,
                              void* d_out, int out_size, void* d_ws, size_t ws_size,
                              hipStream_t stream) {
    const float4* za4 = (const float4*)d_in[0];
    const float4* zb4 = (const float4*)d_in[1];
    float* out = (float*)d_out;
    float* partial = (float*)d_ws;   // BLOCKS floats of scratch
    const int n = in_sizes[0] / D_DIM;

    dot_loss_partial<<<BLOCKS, 256, 0, stream>>>(za4, zb4, partial, n);
    reduce_partials<<<1, 256, 0, stream>>>(partial, out, BLOCKS);
}